// Round 7
// baseline (6315.507 us; speedup 1.0000x reference)
//
#include <hip/hip_runtime.h>
#include <hip/hip_bf16.h>

typedef __attribute__((ext_vector_type(8))) short short8;
typedef __attribute__((ext_vector_type(4))) float floatx4;

#define IN_DIM  4096
#define OUT_DIM 4096
#define MROWS   16384
#define GSIZE   128

template <int N> struct IC { static constexpr int value = N; };

__device__ __forceinline__ unsigned short f2bf(float f) {
    unsigned int u = __builtin_bit_cast(unsigned int, f);
    u = (u + 0x7fffu + ((u >> 16) & 1u)) >> 16;
    return (unsigned short)u;
}

#define GLD16(gsrc, ldst)                                                     \
    __builtin_amdgcn_global_load_lds(                                         \
        (const __attribute__((address_space(1))) unsigned int*)(const void*)(gsrc), \
        (__attribute__((address_space(3))) unsigned int*)(void*)(ldst),       \
        16, 0, 0)

// ---------------------------------------------------------------- convert x
__global__ void convert_x(const float* __restrict__ x,
                          unsigned short* __restrict__ xb, int n8) {
    int stride = gridDim.x * blockDim.x;
    for (int i = blockIdx.x * blockDim.x + threadIdx.x; i < n8; i += stride) {
        const float4* xf = (const float4*)x;
        float4 f0 = xf[2 * i];
        float4 f1 = xf[2 * i + 1];
        union { unsigned short u[8]; uint4 v; } pk;
        pk.u[0] = f2bf(f0.x); pk.u[1] = f2bf(f0.y);
        pk.u[2] = f2bf(f0.z); pk.u[3] = f2bf(f0.w);
        pk.u[4] = f2bf(f1.x); pk.u[5] = f2bf(f1.y);
        pk.u[6] = f2bf(f1.z); pk.u[7] = f2bf(f1.w);
        ((uint4*)xb)[i] = pk.v;
    }
}

// ---------------------------------------------------------------- decode W
__global__ void decode_w(const int* __restrict__ pw,
                         const float* __restrict__ norms,
                         const float* __restrict__ s1,
                         const float* __restrict__ s2,
                         const float* __restrict__ cent,
                         unsigned short* __restrict__ W) {
    int row  = blockIdx.x * 4 + (threadIdx.x >> 6);
    int lane = threadIdx.x & 63;
    float nrm = norms[row];
    int c0 = pw[(size_t)row * GSIZE + lane];
    int c1 = pw[(size_t)row * GSIZE + lane + 64];
    float e0 = cent[c0] * nrm * s2[lane];
    float e1 = cent[c1] * nrm * s2[lane + 64];
#pragma unroll
    for (int it = 0; it < 7; ++it) {
        float a = e0, b = e1;
        e0 = a + b;
        e1 = a - b;
    }
    const float inv = 0.08838834764831845f; // 1/sqrt(128)
    int o = row >> 5, g = row & 31;
    unsigned short* wr = W + (size_t)o * IN_DIM + g * GSIZE;
    wr[lane]      = f2bf(e0 * inv * s1[lane]);
    wr[lane + 64] = f2bf(e1 * inv * s1[lane + 64]);
}

// ---------------------------------------------------------------- GEMM
// 256x256 tile, BK=64, 8 waves (2M x 4N). Minimal-control pipeline:
// only hazard waits are pinned (2 barriers/K-tile); ALL operand waits are
// left to the compiler's exact counted lgkmcnt, so next-slice ds_reads
// drain UNDER the current MFMA cluster. ks-split register double-buffer
// (a_/b_[*][ks]) renames away read/consume conflicts.
//
// Per K-tile j (BF = j&1), per wave:
//   MFMA ks0(j)            (operands read last tile; counted lgkm by compiler)
//   lgkmcnt(0)             (WAR cert: all my reads of BF complete)
//   barrier #1 + fence     (BF free block-wide)
//   STG(j+2 -> BF)         (8 global_load_lds)
//   vmcnt(8) cold          (tile j+1 loads, issued 1 tile ago, all landed)
//   barrier #2 + fence     (RAW globalized: tile j+1 readable)
//   issue ds_read ks0(j+1) (12 reads, drain under MFMA ks1)
//   MFMA ks1(j)
//   issue ds_read ks1(j+1) (12 reads, drain into next tile's MFMA ks0)
__global__ __launch_bounds__(512, 2)
void gemm_bf16(const unsigned short* __restrict__ Xg,
               const unsigned short* __restrict__ Wg,
               const float* __restrict__ bias,
               float* __restrict__ out) {
    __shared__ unsigned short As[2][256][64];
    __shared__ unsigned short Bs[2][256][64];

    // bijective XCD swizzle (1024 blocks % 8 == 0); consecutive ids share mt
    int id = (blockIdx.x & 7) * 128 + (blockIdx.x >> 3);
    int mt = id >> 4, nt = id & 15;
    int m0 = mt * 256, n0 = nt * 256;

    int tid  = threadIdx.x;
    int lane = tid & 63;
    int wid  = tid >> 6;
    int wm = wid >> 2, wn = wid & 3;   // wave tile: rows wm*128+, cols wn*64+

    // staging: thread handles 16B phys chunk cp0 of rows sr0 / sr0+64(+128)
    int sr0 = tid >> 3;        // 0..63
    int cp0 = tid & 7;         // physical chunk position
    int sg0 = cp0 ^ (sr0 & 7); // global chunk (inverse swizzle)

#define STG_AH(bufc, h, j) do {                                               \
    const unsigned short* _s =                                                \
        Xg + (size_t)(m0 + (h)*64 + sr0) * IN_DIM + (size_t)(j)*64 + sg0*8;   \
    GLD16(_s,                 &As[bufc][(h)*64 + sr0][cp0 * 8]);              \
    GLD16(_s + 128 * IN_DIM,  &As[bufc][128 + (h)*64 + sr0][cp0 * 8]);        \
  } while (0)
#define STG_BH(bufc, h, j) do {                                               \
    const unsigned short* _s =                                                \
        Wg + (size_t)(n0 + (h)*128 + sr0) * IN_DIM + (size_t)(j)*64 + sg0*8;  \
    GLD16(_s,                &Bs[bufc][(h)*128 + sr0][cp0 * 8]);              \
    GLD16(_s + 64 * IN_DIM,  &Bs[bufc][(h)*128 + sr0 + 64][cp0 * 8]);         \
  } while (0)
#define STG_TILE(bufc, j) do {                                                \
    STG_BH(bufc, 0, j); STG_BH(bufc, 1, j);                                   \
    STG_AH(bufc, 0, j); STG_AH(bufc, 1, j);                                   \
  } while (0)

    int rl = lane & 15, kc = lane >> 4;
    short8 a_[8][2], b_[4][2];
    floatx4 acc[8][4] = {};

#define LD_A(BFc, m, ks) do {                                                 \
    int row_ = wm * 128 + (m)*16 + rl;                                        \
    a_[m][ks] = *(const short8*)&As[BFc][row_][((((ks)*4 + kc) ^ (row_ & 7)) << 3)]; \
  } while (0)
#define LD_B(BFc, n, ks) do {                                                 \
    int row_ = wn * 64 + (n)*16 + rl;                                         \
    b_[n][ks] = *(const short8*)&Bs[BFc][row_][((((ks)*4 + kc) ^ (row_ & 7)) << 3)]; \
  } while (0)
#define LD_SLICE(BFc, ks) do {                                                \
    LD_B(BFc, 0, ks); LD_B(BFc, 1, ks); LD_B(BFc, 2, ks); LD_B(BFc, 3, ks);   \
    LD_A(BFc, 0, ks); LD_A(BFc, 1, ks); LD_A(BFc, 2, ks); LD_A(BFc, 3, ks);   \
    LD_A(BFc, 4, ks); LD_A(BFc, 5, ks); LD_A(BFc, 6, ks); LD_A(BFc, 7, ks);   \
  } while (0)

#define MFMA_KS(ks) do {                                                      \
    __builtin_amdgcn_s_setprio(1);                                            \
    _Pragma("unroll") for (int m = 0; m < 8; ++m) {                           \
      _Pragma("unroll") for (int n = 0; n < 4; ++n)                           \
        acc[m][n] = __builtin_amdgcn_mfma_f32_16x16x32_bf16(                  \
            a_[m][ks], b_[n][ks], acc[m][n], 0, 0, 0);                        \
    }                                                                         \
    __builtin_amdgcn_s_setprio(0);                                            \
  } while (0)

    // ---- prologue: stage tiles 0,1; certify tile0; prefetch both ks of 0
    STG_TILE(0, 0);
    STG_TILE(1, 1);
    asm volatile("s_waitcnt vmcnt(8)" ::: "memory");  // tile0 resident
    __builtin_amdgcn_s_barrier();
    asm volatile("" ::: "memory");
    LD_SLICE(0, 0);
    LD_SLICE(0, 1);

    // MODE: 2 = steady; 1 = j=62 (no STG, vmcnt(0), still prefetch j+1);
    //       0 = j=63 (tail: no sync, no prefetch)
    auto body = [&](int j, auto bfc, auto modec) {
        constexpr int BF   = decltype(bfc)::value;
        constexpr int MODE = decltype(modec)::value;
        MFMA_KS(0);                                   // counted lgkm by compiler
        if constexpr (MODE >= 1) {
            asm volatile("s_waitcnt lgkmcnt(0)" ::: "memory"); // my BF reads done
            __builtin_amdgcn_s_barrier();                       // #1: BF free
            asm volatile("" ::: "memory");
            if constexpr (MODE == 2) {
                STG_TILE(BF, j + 2);
                asm volatile("s_waitcnt vmcnt(8)" ::: "memory"); // j+1 landed
            } else {
                asm volatile("s_waitcnt vmcnt(0)" ::: "memory"); // j+1 landed
            }
            __builtin_amdgcn_s_barrier();                       // #2: j+1 readable
            asm volatile("" ::: "memory");
            LD_SLICE(BF ^ 1, 0);                                // ks0(j+1)
        }
        MFMA_KS(1);
        if constexpr (MODE >= 1) LD_SLICE(BF ^ 1, 1);           // ks1(j+1)
    };

    for (int j = 0; j < 62; j += 2) {
        body(j,     IC<0>{}, IC<2>{});
        body(j + 1, IC<1>{}, IC<2>{});
    }
    body(62, IC<0>{}, IC<1>{});
    body(63, IC<1>{}, IC<0>{});

    // ---- epilogue: C/D layout col = lane&15, row = (lane>>4)*4 + i
    int q = lane >> 4;
#pragma unroll
    for (int n = 0; n < 4; ++n) {
        int col = n0 + wn * 64 + n * 16 + rl;
        float bv = bias[col];
#pragma unroll
        for (int m = 0; m < 8; ++m) {
#pragma unroll
            for (int i = 0; i < 4; ++i) {
                int row = m0 + wm * 128 + m * 16 + q * 4 + i;
                out[(size_t)row * OUT_DIM + col] = acc[m][n][i] + bv;
            }
        }
    }
#undef STG_AH
#undef STG_BH
#undef STG_TILE
#undef LD_A
#undef LD_B
#undef LD_SLICE
#undef MFMA_KS
}

// ---------------------------------------------------------------- launch
extern "C" void kernel_launch(void* const* d_in, const int* in_sizes, int n_in,
                              void* d_out, int out_size, void* d_ws, size_t ws_size,
                              hipStream_t stream) {
    const float* x     = (const float*)d_in[0];
    const int*   pw    = (const int*)d_in[1];
    const float* norms = (const float*)d_in[2];
    const float* s1    = (const float*)d_in[3];
    const float* s2    = (const float*)d_in[4];
    const float* cent  = (const float*)d_in[5];
    const float* bias  = (const float*)d_in[6];
    float* out = (float*)d_out;

    size_t needX = (size_t)MROWS * IN_DIM * 2;    // 128 MB
    size_t needW = (size_t)OUT_DIM * IN_DIM * 2;  //  32 MB
    if (ws_size < needX + needW) return;

    unsigned short* Xb = (unsigned short*)d_ws;
    unsigned short* Wb = (unsigned short*)((char*)d_ws + needX);

    convert_x<<<2048, 256, 0, stream>>>(x, Xb, MROWS * IN_DIM / 8);
    decode_w<<<(OUT_DIM * 32) / 4, 256, 0, stream>>>(pw, norms, s1, s2, cent, Wb);
    gemm_bf16<<<(MROWS / 256) * (OUT_DIM / 256), 512, 0, stream>>>(Xb, Wb, bias, out);
}